// Round 1
// baseline (6442.686 us; speedup 1.0000x reference)
//
#include <hip/hip_runtime.h>
#include <hip/hip_bf16.h>
#include <math.h>

// Problem constants
constexpr int Bn = 8, Sn = 4096, Cn = 1024, Hn = 16, Dn = 64, Kn = 256;
constexpr int BS = Bn * Sn; // 32768

// ---------------------------------------------------------------------------
// Kernel 1: fused QKV shared projection.  Qp/Kp/Vp[b*S+s][d] = tensor . w^T
// GEMM M=32768, N=192 (3x64), K=1024.  Tile 64x192, K-chunk 32.
// ---------------------------------------------------------------------------
__global__ __launch_bounds__(256) void k_qkv(const float* __restrict__ tensor,
    const float* __restrict__ wqp, const float* __restrict__ wkp, const float* __restrict__ wvp,
    float* __restrict__ Qp, float* __restrict__ Kp, float* __restrict__ Vp)
{
    __shared__ float As[64 * 33];
    __shared__ float Ws[192 * 33];
    const int t = threadIdx.x;
    const int tx = t & 15, ty = t >> 4;
    const int m0 = blockIdx.x * 64;
    float acc[4][12];
#pragma unroll
    for (int i = 0; i < 4; i++)
#pragma unroll
        for (int j = 0; j < 12; j++) acc[i][j] = 0.f;

    for (int kc = 0; kc < Cn; kc += 32) {
#pragma unroll
        for (int ii = 0; ii < 2; ii++) {
            int idx4 = t + ii * 256;
            int row = idx4 >> 3, col4 = idx4 & 7;
            float4 v = *reinterpret_cast<const float4*>(&tensor[(size_t)(m0 + row) * Cn + kc + col4 * 4]);
            float* d2 = &As[row * 33 + col4 * 4];
            d2[0] = v.x; d2[1] = v.y; d2[2] = v.z; d2[3] = v.w;
        }
#pragma unroll
        for (int ii = 0; ii < 6; ii++) {
            int idx4 = t + ii * 256;
            int row = idx4 >> 3, col4 = idx4 & 7;
            const float* src = (row < 64) ? wqp : (row < 128) ? wkp : wvp;
            int srow = row & 63;
            float4 v = *reinterpret_cast<const float4*>(&src[(size_t)srow * Cn + kc + col4 * 4]);
            float* d2 = &Ws[row * 33 + col4 * 4];
            d2[0] = v.x; d2[1] = v.y; d2[2] = v.z; d2[3] = v.w;
        }
        __syncthreads();
#pragma unroll 8
        for (int kk = 0; kk < 32; kk++) {
            float a[4], w[12];
#pragma unroll
            for (int i = 0; i < 4; i++) a[i] = As[(ty * 4 + i) * 33 + kk];
#pragma unroll
            for (int j = 0; j < 12; j++) w[j] = Ws[(tx * 12 + j) * 33 + kk];
#pragma unroll
            for (int i = 0; i < 4; i++)
#pragma unroll
                for (int j = 0; j < 12; j++) acc[i][j] = fmaf(a[i], w[j], acc[i][j]);
        }
        __syncthreads();
    }
#pragma unroll
    for (int i = 0; i < 4; i++) {
        int row = m0 + ty * 4 + i;
#pragma unroll
        for (int j = 0; j < 12; j++) {
            int n = tx * 12 + j;
            float* dst = (n < 64) ? Qp : (n < 128) ? Kp : Vp;
            dst[(size_t)row * Dn + (n & 63)] = acc[i][j];
        }
    }
}

// ---------------------------------------------------------------------------
// Kernel 2: row sums of E_w and F_w over S (needed for bias propagation).
// ---------------------------------------------------------------------------
__global__ __launch_bounds__(256) void k_rowsum(const float* __restrict__ E, const float* __restrict__ F,
                                                float* __restrict__ sumE, float* __restrict__ sumF)
{
    __shared__ float red[256];
    const float* src = blockIdx.y ? F : E;
    float* dst = blockIdx.y ? sumF : sumE;
    const int k = blockIdx.x;
    const int t = threadIdx.x;
    float a = 0.f;
#pragma unroll
    for (int i = 0; i < 16; i++) a += src[(size_t)k * Sn + t + i * 256];
    red[t] = a;
    __syncthreads();
    for (int s = 128; s > 0; s >>= 1) {
        if (t < s) red[t] += red[t + s];
        __syncthreads();
    }
    if (t == 0) dst[k] = red[0];
}

// ---------------------------------------------------------------------------
// Kernel 3: sequence compression.  Kc[b,k,d] = sum_s E[k,s] * Kp[b,s,d]
//           (and Vc with F/Vp).  GEMM 256x64, K=4096 per batch.
// ---------------------------------------------------------------------------
__global__ __launch_bounds__(256) void k_compress(const float* __restrict__ E, const float* __restrict__ F,
    const float* __restrict__ Kp, const float* __restrict__ Vp,
    float* __restrict__ Kc, float* __restrict__ Vc)
{
    __shared__ float Es[64 * 33];
    __shared__ float Ps[32 * 64];
    const float* A = blockIdx.z ? F : E;
    const float* Bm = blockIdx.z ? Vp : Kp;
    float* dst = blockIdx.z ? Vc : Kc;
    const int b = blockIdx.y;
    const int k0 = blockIdx.x * 64;
    const int t = threadIdx.x, tx = t & 15, ty = t >> 4;
    float acc[4][4] = {};
    for (int sc = 0; sc < Sn; sc += 32) {
#pragma unroll
        for (int ii = 0; ii < 2; ii++) {
            int idx4 = t + ii * 256;
            int row = idx4 >> 3, col4 = idx4 & 7;
            float4 v = *reinterpret_cast<const float4*>(&A[(size_t)(k0 + row) * Sn + sc + col4 * 4]);
            float* d2 = &Es[row * 33 + col4 * 4];
            d2[0] = v.x; d2[1] = v.y; d2[2] = v.z; d2[3] = v.w;
        }
#pragma unroll
        for (int ii = 0; ii < 2; ii++) {
            int idx4 = t + ii * 256;
            int row = idx4 >> 4, col4 = idx4 & 15;
            float4 v = *reinterpret_cast<const float4*>(&Bm[((size_t)b * Sn + sc + row) * Dn + col4 * 4]);
            float* d2 = &Ps[row * 64 + col4 * 4];
            d2[0] = v.x; d2[1] = v.y; d2[2] = v.z; d2[3] = v.w;
        }
        __syncthreads();
#pragma unroll 8
        for (int kk = 0; kk < 32; kk++) {
            float a[4], w[4];
#pragma unroll
            for (int i = 0; i < 4; i++) a[i] = Es[(ty * 4 + i) * 33 + kk];
#pragma unroll
            for (int j = 0; j < 4; j++) w[j] = Ps[kk * 64 + tx * 4 + j];
#pragma unroll
            for (int i = 0; i < 4; i++)
#pragma unroll
                for (int j = 0; j < 4; j++) acc[i][j] = fmaf(a[i], w[j], acc[i][j]);
        }
        __syncthreads();
    }
#pragma unroll
    for (int i = 0; i < 4; i++) {
        float4 v = make_float4(acc[i][0], acc[i][1], acc[i][2], acc[i][3]);
        *reinterpret_cast<float4*>(&dst[((size_t)b * Kn + k0 + ty * 4 + i) * Dn + tx * 4]) = v;
    }
}

// ---------------------------------------------------------------------------
// Kernel 4: per-head combined weights.
//   Wqk[h,d,dp] = sum_e wq[h,e,d]*wk[h,e,dp]
//   u[h,d] = sum_e wq[h,e,d]*wk_b[h,e];  g[h,d] = sum_e wq[h,e,d]
//   cw[h,dp] = sum_e wq_b[h,e]*wk[h,e,dp];  cu[h], cg[h] similar scalars.
// ---------------------------------------------------------------------------
__global__ __launch_bounds__(256) void k_headw(const float* __restrict__ wq, const float* __restrict__ wqb,
    const float* __restrict__ wk, const float* __restrict__ wkb,
    float* __restrict__ Wqk, float* __restrict__ u, float* __restrict__ g,
    float* __restrict__ cw, float* __restrict__ cu, float* __restrict__ cg)
{
    __shared__ float wqL[64 * 64], wkL[64 * 64];
    const int h = blockIdx.x, t = threadIdx.x;
#pragma unroll
    for (int ii = 0; ii < 4; ii++) {
        int idx4 = (t + ii * 256) * 4;
        *reinterpret_cast<float4*>(&wqL[idx4]) = *reinterpret_cast<const float4*>(&wq[(size_t)h * 4096 + idx4]);
        *reinterpret_cast<float4*>(&wkL[idx4]) = *reinterpret_cast<const float4*>(&wk[(size_t)h * 4096 + idx4]);
    }
    __syncthreads();
#pragma unroll 2
    for (int ii = 0; ii < 16; ii++) {
        int idx = t + ii * 256;
        int d = idx >> 6, dp = idx & 63;
        float acc = 0.f;
        for (int e = 0; e < 64; e++) acc = fmaf(wqL[e * 64 + d], wkL[e * 64 + dp], acc);
        Wqk[(size_t)h * 4096 + idx] = acc;
    }
    if (t < 64) {
        int d = t;
        float au = 0.f, ag = 0.f, aw = 0.f;
        for (int e = 0; e < 64; e++) {
            float q = wqL[e * 64 + d];
            au = fmaf(q, wkb[h * 64 + e], au);
            ag += q;
            aw = fmaf(wqb[h * 64 + e], wkL[e * 64 + d], aw);
        }
        u[h * 64 + d] = au; g[h * 64 + d] = ag; cw[h * 64 + d] = aw;
    }
    if (t == 0) {
        float acu = 0.f, acg = 0.f;
        for (int e = 0; e < 64; e++) {
            acu = fmaf(wqb[h * 64 + e], wkb[h * 64 + e], acu);
            acg += wqb[h * 64 + e];
        }
        cu[h] = acu; cg[h] = acg;
    }
}

// ---------------------------------------------------------------------------
// Kernel 5: KEq[b,h,d,k] = sum_dp Wqk[h,d,dp]*Kc[b,k,dp] + u*sumE[k] + g*E_b[k]
//           c0[b,h,k]   = sum_dp cw[h,dp]*Kc[b,k,dp] + cu*sumE[k] + cg*E_b[k]
// One block per (h,b); thread = k.
// ---------------------------------------------------------------------------
__global__ __launch_bounds__(256) void k_keq(const float* __restrict__ Kc,
    const float* __restrict__ Wqk, const float* __restrict__ u, const float* __restrict__ g,
    const float* __restrict__ cw, const float* __restrict__ cu, const float* __restrict__ cg,
    const float* __restrict__ sumE, const float* __restrict__ Eb,
    float* __restrict__ KEq, float* __restrict__ c0)
{
    extern __shared__ float KcT[]; // [64][256]
    const int h = blockIdx.x, b = blockIdx.y;
    const int bh = b * Hn + h;
    const int t = threadIdx.x;
#pragma unroll 8
    for (int ii = 0; ii < 64; ii++) {
        int idx = t + ii * 256;
        int kr = idx >> 6, dp = idx & 63;
        KcT[dp * 256 + kr] = Kc[((size_t)b * Kn + kr) * 64 + dp];
    }
    __syncthreads();
    const float sE = sumE[t], eb = Eb[t];
    for (int d = 0; d < 64; d++) {
        float acc = 0.f;
#pragma unroll
        for (int dp4 = 0; dp4 < 16; dp4++) {
            float4 w = *reinterpret_cast<const float4*>(&Wqk[(size_t)h * 4096 + d * 64 + dp4 * 4]);
            acc = fmaf(w.x, KcT[(dp4 * 4 + 0) * 256 + t], acc);
            acc = fmaf(w.y, KcT[(dp4 * 4 + 1) * 256 + t], acc);
            acc = fmaf(w.z, KcT[(dp4 * 4 + 2) * 256 + t], acc);
            acc = fmaf(w.w, KcT[(dp4 * 4 + 3) * 256 + t], acc);
        }
        KEq[((size_t)bh * 64 + d) * 256 + t] = acc + u[h * 64 + d] * sE + g[h * 64 + d] * eb;
    }
    float acc = 0.f;
#pragma unroll
    for (int dp4 = 0; dp4 < 16; dp4++) {
        float4 w = *reinterpret_cast<const float4*>(&cw[h * 64 + dp4 * 4]);
        acc = fmaf(w.x, KcT[(dp4 * 4 + 0) * 256 + t], acc);
        acc = fmaf(w.y, KcT[(dp4 * 4 + 1) * 256 + t], acc);
        acc = fmaf(w.z, KcT[(dp4 * 4 + 2) * 256 + t], acc);
        acc = fmaf(w.w, KcT[(dp4 * 4 + 3) * 256 + t], acc);
    }
    c0[(size_t)bh * 256 + t] = acc + cu[h] * sE + cg[h] * eb;
}

// ---------------------------------------------------------------------------
// Kernel 6: VF[b,h,k,e] = sum_dp wv[h,e,dp]*Vc[b,k,dp] + wv_b[h,e]*sumF[k] + F_b[k]
// ---------------------------------------------------------------------------
__global__ __launch_bounds__(256) void k_vf(const float* __restrict__ Vc,
    const float* __restrict__ wv, const float* __restrict__ wvb,
    const float* __restrict__ sumF, const float* __restrict__ Fb,
    float* __restrict__ VF)
{
    extern __shared__ float VcT[]; // [64][256]
    const int h = blockIdx.x, b = blockIdx.y;
    const int bh = b * Hn + h;
    const int t = threadIdx.x;
#pragma unroll 8
    for (int ii = 0; ii < 64; ii++) {
        int idx = t + ii * 256;
        int kr = idx >> 6, dp = idx & 63;
        VcT[dp * 256 + kr] = Vc[((size_t)b * Kn + kr) * 64 + dp];
    }
    __syncthreads();
    const float sF = sumF[t], fb = Fb[t];
    for (int e = 0; e < 64; e++) {
        float acc = 0.f;
#pragma unroll
        for (int dp4 = 0; dp4 < 16; dp4++) {
            float4 w = *reinterpret_cast<const float4*>(&wv[(size_t)h * 4096 + e * 64 + dp4 * 4]);
            acc = fmaf(w.x, VcT[(dp4 * 4 + 0) * 256 + t], acc);
            acc = fmaf(w.y, VcT[(dp4 * 4 + 1) * 256 + t], acc);
            acc = fmaf(w.z, VcT[(dp4 * 4 + 2) * 256 + t], acc);
            acc = fmaf(w.w, VcT[(dp4 * 4 + 3) * 256 + t], acc);
        }
        VF[((size_t)bh * 256 + t) * 64 + e] = acc + wvb[h * 64 + e] * sF + fb;
    }
}

// ---------------------------------------------------------------------------
// Kernel 7: attention core.  scores = (Qp . KEq + c0)/8 ; softmax over K=256 ;
// out_h = P . VF ; exact GELU ; store bf16 into cat[b,s,h*64+e].
// Block: 32 s-rows of one (b,h).  Thread (r,g): r=row, g=1/8 of K or D.
// ---------------------------------------------------------------------------
__global__ __launch_bounds__(256) void k_attn(const float* __restrict__ Qp,
    const float* __restrict__ KEq, const float* __restrict__ c0,
    const float* __restrict__ VF, __hip_bfloat16* __restrict__ cat)
{
    __shared__ float QL[32 * 66];
    __shared__ float PL[32 * 258];
    __shared__ float linvL[32];
    const int bh = blockIdx.y;
    const int b = bh >> 4, h = bh & 15;
    const int s0 = blockIdx.x * 32;
    const int t = threadIdx.x;
    const int r = t >> 3, gg = t & 7;

#pragma unroll
    for (int ii = 0; ii < 2; ii++) {
        int idx4 = t + ii * 256;
        int row = idx4 >> 4, c4 = idx4 & 15;
        float4 v = *reinterpret_cast<const float4*>(&Qp[((size_t)b * Sn + s0 + row) * 64 + c4 * 4]);
        float* d2 = &QL[row * 66 + c4 * 4];
        d2[0] = v.x; d2[1] = v.y; d2[2] = v.z; d2[3] = v.w;
    }
    __syncthreads();

    float sc[32];
#pragma unroll
    for (int i = 0; i < 32; i++) sc[i] = 0.f;
    const float* keqBase = &KEq[(size_t)bh * 64 * 256 + gg * 32];
    for (int d = 0; d < 64; d++) {
        float q = QL[r * 66 + d];
        const float4* kp = reinterpret_cast<const float4*>(keqBase + (size_t)d * 256);
#pragma unroll
        for (int k4 = 0; k4 < 8; k4++) {
            float4 kv = kp[k4];
            sc[k4 * 4 + 0] = fmaf(q, kv.x, sc[k4 * 4 + 0]);
            sc[k4 * 4 + 1] = fmaf(q, kv.y, sc[k4 * 4 + 1]);
            sc[k4 * 4 + 2] = fmaf(q, kv.z, sc[k4 * 4 + 2]);
            sc[k4 * 4 + 3] = fmaf(q, kv.w, sc[k4 * 4 + 3]);
        }
    }
    const float4* cp = reinterpret_cast<const float4*>(&c0[(size_t)bh * 256 + gg * 32]);
#pragma unroll
    for (int k4 = 0; k4 < 8; k4++) {
        float4 cv = cp[k4];
        sc[k4 * 4 + 0] = (sc[k4 * 4 + 0] + cv.x) * 0.125f;
        sc[k4 * 4 + 1] = (sc[k4 * 4 + 1] + cv.y) * 0.125f;
        sc[k4 * 4 + 2] = (sc[k4 * 4 + 2] + cv.z) * 0.125f;
        sc[k4 * 4 + 3] = (sc[k4 * 4 + 3] + cv.w) * 0.125f;
    }
    // softmax over the row (8 threads x 32 values)
    float m = sc[0];
#pragma unroll
    for (int i = 1; i < 32; i++) m = fmaxf(m, sc[i]);
    m = fmaxf(m, __shfl_xor(m, 1));
    m = fmaxf(m, __shfl_xor(m, 2));
    m = fmaxf(m, __shfl_xor(m, 4));
    float l = 0.f;
#pragma unroll
    for (int i = 0; i < 32; i++) {
        sc[i] = __expf(sc[i] - m);
        l += sc[i];
    }
    l += __shfl_xor(l, 1);
    l += __shfl_xor(l, 2);
    l += __shfl_xor(l, 4);
#pragma unroll
    for (int i = 0; i < 32; i++) PL[r * 258 + gg * 32 + i] = sc[i];
    if (gg == 0) linvL[r] = 1.0f / l;
    __syncthreads();

    // PV: thread (r,g) computes out cols e = g*8 .. g*8+7
    float o[8];
#pragma unroll
    for (int j = 0; j < 8; j++) o[j] = 0.f;
    const float* vfBase = &VF[(size_t)bh * Kn * 64 + gg * 8];
    for (int k = 0; k < 256; k++) {
        float p = PL[r * 258 + k];
        float4 v0 = *reinterpret_cast<const float4*>(vfBase + (size_t)k * 64);
        float4 v1 = *reinterpret_cast<const float4*>(vfBase + (size_t)k * 64 + 4);
        o[0] = fmaf(p, v0.x, o[0]); o[1] = fmaf(p, v0.y, o[1]);
        o[2] = fmaf(p, v0.z, o[2]); o[3] = fmaf(p, v0.w, o[3]);
        o[4] = fmaf(p, v1.x, o[4]); o[5] = fmaf(p, v1.y, o[5]);
        o[6] = fmaf(p, v1.z, o[6]); o[7] = fmaf(p, v1.w, o[7]);
    }
    const float inv = linvL[r];
    union { uint4 u4; __hip_bfloat16 b8[8]; } pk;
#pragma unroll
    for (int j = 0; j < 8; j++) {
        float x = o[j] * inv;
        float y = 0.5f * x * (1.0f + erff(x * 0.70710678118654752f)); // exact GELU
        pk.b8[j] = __float2bfloat16(y);
    }
    *reinterpret_cast<uint4*>(&cat[((size_t)b * Sn + s0 + r) * 1024 + h * 64 + gg * 8]) = pk.u4;
}

// ---------------------------------------------------------------------------
// Kernel 8: final projection.  out[m,c] = sum_f cat[m,f]*wo[c,f] + wo_b[c]
// GEMM M=32768, N=1024, K=1024.  A is bf16 (gelu already applied).
// ---------------------------------------------------------------------------
__global__ __launch_bounds__(256) void k_out(const __hip_bfloat16* __restrict__ cat,
    const float* __restrict__ wo, const float* __restrict__ wob, float* __restrict__ out)
{
    __shared__ float As[64 * 33];
    __shared__ float Bs[64 * 33];
    const int t = threadIdx.x, tx = t & 15, ty = t >> 4;
    const int n0 = blockIdx.x * 64;  // output-feature tile (x fastest -> A tile reused in L2)
    const int m0 = blockIdx.y * 64;  // row tile
    float acc[4][4] = {};
    for (int kc = 0; kc < 1024; kc += 32) {
        {
            int row = t >> 2, c8 = t & 3;
            uint4 v = *reinterpret_cast<const uint4*>(&cat[((size_t)m0 + row) * 1024 + kc + c8 * 8]);
            float* d2 = &As[row * 33 + c8 * 8];
            unsigned arr[4] = {v.x, v.y, v.z, v.w};
#pragma unroll
            for (int w = 0; w < 4; w++) {
                d2[w * 2 + 0] = __uint_as_float(arr[w] << 16);
                d2[w * 2 + 1] = __uint_as_float(arr[w] & 0xFFFF0000u);
            }
        }
#pragma unroll
        for (int ii = 0; ii < 2; ii++) {
            int idx4 = t + ii * 256;
            int row = idx4 >> 3, c4 = idx4 & 7;
            float4 v = *reinterpret_cast<const float4*>(&wo[((size_t)n0 + row) * 1024 + kc + c4 * 4]);
            float* d2 = &Bs[row * 33 + c4 * 4];
            d2[0] = v.x; d2[1] = v.y; d2[2] = v.z; d2[3] = v.w;
        }
        __syncthreads();
#pragma unroll 8
        for (int kk = 0; kk < 32; kk++) {
            float a[4], w[4];
#pragma unroll
            for (int i = 0; i < 4; i++) a[i] = As[(ty * 4 + i) * 33 + kk];
#pragma unroll
            for (int j = 0; j < 4; j++) w[j] = Bs[(tx * 4 + j) * 33 + kk];
#pragma unroll
            for (int i = 0; i < 4; i++)
#pragma unroll
                for (int j = 0; j < 4; j++) acc[i][j] = fmaf(a[i], w[j], acc[i][j]);
        }
        __syncthreads();
    }
#pragma unroll
    for (int i = 0; i < 4; i++) {
        int row = m0 + ty * 4 + i;
        float4 v;
        v.x = acc[i][0] + wob[n0 + tx * 4 + 0];
        v.y = acc[i][1] + wob[n0 + tx * 4 + 1];
        v.z = acc[i][2] + wob[n0 + tx * 4 + 2];
        v.w = acc[i][3] + wob[n0 + tx * 4 + 3];
        *reinterpret_cast<float4*>(&out[(size_t)row * 1024 + n0 + tx * 4]) = v;
    }
}

// ---------------------------------------------------------------------------
extern "C" void kernel_launch(void* const* d_in, const int* in_sizes, int n_in,
                              void* d_out, int out_size, void* d_ws, size_t ws_size,
                              hipStream_t stream) {
    const float* tensor = (const float*)d_in[0];
    const float* to_q   = (const float*)d_in[1];
    const float* to_k   = (const float*)d_in[2];
    const float* to_v   = (const float*)d_in[3];
    const float* wq     = (const float*)d_in[4];
    const float* wqb    = (const float*)d_in[5];
    const float* wk     = (const float*)d_in[6];
    const float* wkb    = (const float*)d_in[7];
    const float* wv     = (const float*)d_in[8];
    const float* wvb    = (const float*)d_in[9];
    const float* Ew     = (const float*)d_in[10];
    const float* Eb     = (const float*)d_in[11];
    const float* Fw     = (const float*)d_in[12];
    const float* Fb     = (const float*)d_in[13];
    const float* wo     = (const float*)d_in[14];
    const float* wob    = (const float*)d_in[15];
    float* out = (float*)d_out;

    // workspace layout (floats)
    float* ws   = (float*)d_ws;
    float* Qp   = ws;                 // 2097152
    float* Kp   = Qp + 2097152;       // 2097152
    float* Vp   = Kp + 2097152;       // 2097152
    float* Kc   = Vp + 2097152;       // 131072
    float* Vc   = Kc + 131072;        // 131072
    float* sumE = Vc + 131072;        // 256
    float* sumF = sumE + 256;         // 256
    float* Wqk  = sumF + 256;         // 65536
    float* u    = Wqk + 65536;        // 1024
    float* g    = u + 1024;           // 1024
    float* cw   = g + 1024;           // 1024
    float* cu   = cw + 1024;          // 16
    float* cg   = cu + 16;            // 16
    float* c0   = cg + 16;            // 32768
    float* KEq  = c0 + 32768;         // 2097152
    float* VF   = KEq + 2097152;      // 2097152
    __hip_bfloat16* cat = (__hip_bfloat16*)(VF + 2097152); // 33554432 bf16

    size_t need = (size_t)(VF + 2097152 - ws) * 4 + (size_t)BS * 1024 * 2;
    if (ws_size < need) return; // insufficient workspace -> visible failure, no corruption

    k_qkv<<<dim3(BS / 64), 256, 0, stream>>>(tensor, to_q, to_k, to_v, Qp, Kp, Vp);
    k_rowsum<<<dim3(Kn, 2), 256, 0, stream>>>(Ew, Fw, sumE, sumF);
    k_compress<<<dim3(4, Bn, 2), 256, 0, stream>>>(Ew, Fw, Kp, Vp, Kc, Vc);
    k_headw<<<dim3(Hn), 256, 0, stream>>>(wq, wqb, wk, wkb, Wqk, u, g, cw, cu, cg);
    k_keq<<<dim3(Hn, Bn), 256, 65536, stream>>>(Kc, Wqk, u, g, cw, cu, cg, sumE, Eb, KEq, c0);
    k_vf<<<dim3(Hn, Bn), 256, 65536, stream>>>(Vc, wv, wvb, sumF, Fb, VF);
    k_attn<<<dim3(Sn / 32, Bn * Hn), 256, 0, stream>>>(Qp, KEq, c0, VF, cat);
    k_out<<<dim3(Cn / 64, BS / 64), 256, 0, stream>>>(cat, wo, wob, out);
}

// Round 2
// 1065.615 us; speedup vs baseline: 6.0460x; 6.0460x over previous
//
#include <hip/hip_runtime.h>
#include <hip/hip_bf16.h>
#include <math.h>

// Problem constants
constexpr int Bn = 8, Sn = 4096, Cn = 1024, Hn = 16, Dn = 64, Kn = 256;
constexpr int BS = Bn * Sn; // 32768

typedef __attribute__((ext_vector_type(8))) short bhalf8;
typedef __attribute__((ext_vector_type(4))) float floatx4;

// ---------------------------------------------------------------------------
// Kernel 1: fused QKV shared projection.  Q -> bf16 [s][64]; K,V -> f32.
// GEMM M=32768, N=192 (3x64), K=1024.  Tile 64x192, K-chunk 32.
// ---------------------------------------------------------------------------
__global__ __launch_bounds__(256) void k_qkv(const float* __restrict__ tensor,
    const float* __restrict__ wqp, const float* __restrict__ wkp, const float* __restrict__ wvp,
    __hip_bfloat16* __restrict__ Qb, float* __restrict__ Kp, float* __restrict__ Vp)
{
    __shared__ float As[64 * 33];
    __shared__ float Ws[192 * 33];
    const int t = threadIdx.x;
    const int tx = t & 15, ty = t >> 4;
    const int m0 = blockIdx.x * 64;
    float acc[4][12];
#pragma unroll
    for (int i = 0; i < 4; i++)
#pragma unroll
        for (int j = 0; j < 12; j++) acc[i][j] = 0.f;

    for (int kc = 0; kc < Cn; kc += 32) {
#pragma unroll
        for (int ii = 0; ii < 2; ii++) {
            int idx4 = t + ii * 256;
            int row = idx4 >> 3, col4 = idx4 & 7;
            float4 v = *reinterpret_cast<const float4*>(&tensor[(size_t)(m0 + row) * Cn + kc + col4 * 4]);
            float* d2 = &As[row * 33 + col4 * 4];
            d2[0] = v.x; d2[1] = v.y; d2[2] = v.z; d2[3] = v.w;
        }
#pragma unroll
        for (int ii = 0; ii < 6; ii++) {
            int idx4 = t + ii * 256;
            int row = idx4 >> 3, col4 = idx4 & 7;
            const float* src = (row < 64) ? wqp : (row < 128) ? wkp : wvp;
            int srow = row & 63;
            float4 v = *reinterpret_cast<const float4*>(&src[(size_t)srow * Cn + kc + col4 * 4]);
            float* d2 = &Ws[row * 33 + col4 * 4];
            d2[0] = v.x; d2[1] = v.y; d2[2] = v.z; d2[3] = v.w;
        }
        __syncthreads();
#pragma unroll 8
        for (int kk = 0; kk < 32; kk++) {
            float a[4], w[12];
#pragma unroll
            for (int i = 0; i < 4; i++) a[i] = As[(ty * 4 + i) * 33 + kk];
#pragma unroll
            for (int j = 0; j < 12; j++) w[j] = Ws[(tx * 12 + j) * 33 + kk];
#pragma unroll
            for (int i = 0; i < 4; i++)
#pragma unroll
                for (int j = 0; j < 12; j++) acc[i][j] = fmaf(a[i], w[j], acc[i][j]);
        }
        __syncthreads();
    }
#pragma unroll
    for (int i = 0; i < 4; i++) {
        int row = m0 + ty * 4 + i;
#pragma unroll
        for (int j = 0; j < 12; j++) {
            int n = tx * 12 + j;
            if (n < 64) {
                Qb[(size_t)row * 64 + n] = __float2bfloat16(acc[i][j]);
            } else {
                float* dst = (n < 128) ? Kp : Vp;
                dst[(size_t)row * Dn + (n & 63)] = acc[i][j];
            }
        }
    }
}

// ---------------------------------------------------------------------------
// Kernel 2: row sums of E_w and F_w over S.
// ---------------------------------------------------------------------------
__global__ __launch_bounds__(256) void k_rowsum(const float* __restrict__ E, const float* __restrict__ F,
                                                float* __restrict__ sumE, float* __restrict__ sumF)
{
    __shared__ float red[256];
    const float* src = blockIdx.y ? F : E;
    float* dst = blockIdx.y ? sumF : sumE;
    const int k = blockIdx.x;
    const int t = threadIdx.x;
    float a = 0.f;
#pragma unroll
    for (int i = 0; i < 16; i++) a += src[(size_t)k * Sn + t + i * 256];
    red[t] = a;
    __syncthreads();
    for (int s = 128; s > 0; s >>= 1) {
        if (t < s) red[t] += red[t + s];
        __syncthreads();
    }
    if (t == 0) dst[k] = red[0];
}

// ---------------------------------------------------------------------------
// Kernel 3: sequence compression.  Kc[b,k,d] = sum_s E[k,s] * Kp[b,s,d]
// ---------------------------------------------------------------------------
__global__ __launch_bounds__(256) void k_compress(const float* __restrict__ E, const float* __restrict__ F,
    const float* __restrict__ Kp, const float* __restrict__ Vp,
    float* __restrict__ Kc, float* __restrict__ Vc)
{
    __shared__ float Es[64 * 33];
    __shared__ float Ps[32 * 64];
    const float* A = blockIdx.z ? F : E;
    const float* Bm = blockIdx.z ? Vp : Kp;
    float* dst = blockIdx.z ? Vc : Kc;
    const int b = blockIdx.y;
    const int k0 = blockIdx.x * 64;
    const int t = threadIdx.x, tx = t & 15, ty = t >> 4;
    float acc[4][4] = {};
    for (int sc = 0; sc < Sn; sc += 32) {
#pragma unroll
        for (int ii = 0; ii < 2; ii++) {
            int idx4 = t + ii * 256;
            int row = idx4 >> 3, col4 = idx4 & 7;
            float4 v = *reinterpret_cast<const float4*>(&A[(size_t)(k0 + row) * Sn + sc + col4 * 4]);
            float* d2 = &Es[row * 33 + col4 * 4];
            d2[0] = v.x; d2[1] = v.y; d2[2] = v.z; d2[3] = v.w;
        }
#pragma unroll
        for (int ii = 0; ii < 2; ii++) {
            int idx4 = t + ii * 256;
            int row = idx4 >> 4, col4 = idx4 & 15;
            float4 v = *reinterpret_cast<const float4*>(&Bm[((size_t)b * Sn + sc + row) * Dn + col4 * 4]);
            float* d2 = &Ps[row * 64 + col4 * 4];
            d2[0] = v.x; d2[1] = v.y; d2[2] = v.z; d2[3] = v.w;
        }
        __syncthreads();
#pragma unroll 8
        for (int kk = 0; kk < 32; kk++) {
            float a[4], w[4];
#pragma unroll
            for (int i = 0; i < 4; i++) a[i] = Es[(ty * 4 + i) * 33 + kk];
#pragma unroll
            for (int j = 0; j < 4; j++) w[j] = Ps[kk * 64 + tx * 4 + j];
#pragma unroll
            for (int i = 0; i < 4; i++)
#pragma unroll
                for (int j = 0; j < 4; j++) acc[i][j] = fmaf(a[i], w[j], acc[i][j]);
        }
        __syncthreads();
    }
#pragma unroll
    for (int i = 0; i < 4; i++) {
        float4 v = make_float4(acc[i][0], acc[i][1], acc[i][2], acc[i][3]);
        *reinterpret_cast<float4*>(&dst[((size_t)b * Kn + k0 + ty * 4 + i) * Dn + tx * 4]) = v;
    }
}

// ---------------------------------------------------------------------------
// Kernel 4: per-head combined weights (Wqk = wq^T wk, plus bias folds).
// ---------------------------------------------------------------------------
__global__ __launch_bounds__(256) void k_headw(const float* __restrict__ wq, const float* __restrict__ wqb,
    const float* __restrict__ wk, const float* __restrict__ wkb,
    float* __restrict__ Wqk, float* __restrict__ u, float* __restrict__ g,
    float* __restrict__ cw, float* __restrict__ cu, float* __restrict__ cg)
{
    __shared__ float wqL[64 * 64], wkL[64 * 64];
    const int h = blockIdx.x, t = threadIdx.x;
#pragma unroll
    for (int ii = 0; ii < 4; ii++) {
        int idx4 = (t + ii * 256) * 4;
        *reinterpret_cast<float4*>(&wqL[idx4]) = *reinterpret_cast<const float4*>(&wq[(size_t)h * 4096 + idx4]);
        *reinterpret_cast<float4*>(&wkL[idx4]) = *reinterpret_cast<const float4*>(&wk[(size_t)h * 4096 + idx4]);
    }
    __syncthreads();
#pragma unroll 2
    for (int ii = 0; ii < 16; ii++) {
        int idx = t + ii * 256;
        int d = idx >> 6, dp = idx & 63;
        float acc = 0.f;
        for (int e = 0; e < 64; e++) acc = fmaf(wqL[e * 64 + d], wkL[e * 64 + dp], acc);
        Wqk[(size_t)h * 4096 + idx] = acc;
    }
    if (t < 64) {
        int d = t;
        float au = 0.f, ag = 0.f, aw = 0.f;
        for (int e = 0; e < 64; e++) {
            float q = wqL[e * 64 + d];
            au = fmaf(q, wkb[h * 64 + e], au);
            ag += q;
            aw = fmaf(wqb[h * 64 + e], wkL[e * 64 + d], aw);
        }
        u[h * 64 + d] = au; g[h * 64 + d] = ag; cw[h * 64 + d] = aw;
    }
    if (t == 0) {
        float acu = 0.f, acg = 0.f;
        for (int e = 0; e < 64; e++) {
            acu = fmaf(wqb[h * 64 + e], wkb[h * 64 + e], acu);
            acg += wqb[h * 64 + e];
        }
        cu[h] = acu; cg[h] = acg;
    }
}

// ---------------------------------------------------------------------------
// Kernel 5: KEqT[b,h,k,d] (bf16) = sum_dp Wqk[h,d,dp]*Kc[b,k,dp] + u*sumE[k] + g*E_b[k]
//           c0[b,h,k] (f32)
// One block per (h,b); thread = k.
// ---------------------------------------------------------------------------
__global__ __launch_bounds__(256) void k_keq(const float* __restrict__ Kc,
    const float* __restrict__ Wqk, const float* __restrict__ u, const float* __restrict__ g,
    const float* __restrict__ cw, const float* __restrict__ cu, const float* __restrict__ cg,
    const float* __restrict__ sumE, const float* __restrict__ Eb,
    __hip_bfloat16* __restrict__ KEqT, float* __restrict__ c0)
{
    extern __shared__ float KcT[]; // [64][256]
    const int h = blockIdx.x, b = blockIdx.y;
    const int bh = b * Hn + h;
    const int t = threadIdx.x;
#pragma unroll 8
    for (int ii = 0; ii < 64; ii++) {
        int idx = t + ii * 256;
        int kr = idx >> 6, dp = idx & 63;
        KcT[dp * 256 + kr] = Kc[((size_t)b * Kn + kr) * 64 + dp];
    }
    __syncthreads();
    const float sE = sumE[t], eb = Eb[t];
    for (int d = 0; d < 64; d++) {
        float acc = 0.f;
#pragma unroll
        for (int dp4 = 0; dp4 < 16; dp4++) {
            float4 w = *reinterpret_cast<const float4*>(&Wqk[(size_t)h * 4096 + d * 64 + dp4 * 4]);
            acc = fmaf(w.x, KcT[(dp4 * 4 + 0) * 256 + t], acc);
            acc = fmaf(w.y, KcT[(dp4 * 4 + 1) * 256 + t], acc);
            acc = fmaf(w.z, KcT[(dp4 * 4 + 2) * 256 + t], acc);
            acc = fmaf(w.w, KcT[(dp4 * 4 + 3) * 256 + t], acc);
        }
        float val = acc + u[h * 64 + d] * sE + g[h * 64 + d] * eb;
        KEqT[((size_t)bh * 256 + t) * 64 + d] = __float2bfloat16(val);
    }
    float acc = 0.f;
#pragma unroll
    for (int dp4 = 0; dp4 < 16; dp4++) {
        float4 w = *reinterpret_cast<const float4*>(&cw[h * 64 + dp4 * 4]);
        acc = fmaf(w.x, KcT[(dp4 * 4 + 0) * 256 + t], acc);
        acc = fmaf(w.y, KcT[(dp4 * 4 + 1) * 256 + t], acc);
        acc = fmaf(w.z, KcT[(dp4 * 4 + 2) * 256 + t], acc);
        acc = fmaf(w.w, KcT[(dp4 * 4 + 3) * 256 + t], acc);
    }
    c0[(size_t)bh * 256 + t] = acc + cu[h] * sE + cg[h] * eb;
}

// ---------------------------------------------------------------------------
// Kernel 6: VFT[b,h,d,k] (bf16) = VF[k,d] = sum_dp wv[h,d,dp]*Vc[b,k,dp] + wv_b*sumF[k] + F_b[k]
// thread = k; loop over output dim e; write VFT[e][k] -> coalesced over t.
// ---------------------------------------------------------------------------
__global__ __launch_bounds__(256) void k_vf(const float* __restrict__ Vc,
    const float* __restrict__ wv, const float* __restrict__ wvb,
    const float* __restrict__ sumF, const float* __restrict__ Fb,
    __hip_bfloat16* __restrict__ VFT)
{
    extern __shared__ float VcT[]; // [64][256]
    const int h = blockIdx.x, b = blockIdx.y;
    const int bh = b * Hn + h;
    const int t = threadIdx.x;
#pragma unroll 8
    for (int ii = 0; ii < 64; ii++) {
        int idx = t + ii * 256;
        int kr = idx >> 6, dp = idx & 63;
        VcT[dp * 256 + kr] = Vc[((size_t)b * Kn + kr) * 64 + dp];
    }
    __syncthreads();
    const float sF = sumF[t], fb = Fb[t];
    for (int e = 0; e < 64; e++) {
        float acc = 0.f;
#pragma unroll
        for (int dp4 = 0; dp4 < 16; dp4++) {
            float4 w = *reinterpret_cast<const float4*>(&wv[(size_t)h * 4096 + e * 64 + dp4 * 4]);
            acc = fmaf(w.x, VcT[(dp4 * 4 + 0) * 256 + t], acc);
            acc = fmaf(w.y, VcT[(dp4 * 4 + 1) * 256 + t], acc);
            acc = fmaf(w.z, VcT[(dp4 * 4 + 2) * 256 + t], acc);
            acc = fmaf(w.w, VcT[(dp4 * 4 + 3) * 256 + t], acc);
        }
        VFT[(size_t)bh * 16384 + e * 256 + t] = __float2bfloat16(acc + wvb[h * 64 + e] * sF + fb);
    }
}

// ---------------------------------------------------------------------------
// Kernel 6b: cast wo (f32 [c][f]) -> bf16
// ---------------------------------------------------------------------------
__global__ __launch_bounds__(256) void k_cast(const float* __restrict__ src, __hip_bfloat16* __restrict__ dst)
{
    int i = (blockIdx.x * 256 + threadIdx.x) * 4;
    float4 v = *reinterpret_cast<const float4*>(src + i);
    union { __hip_bfloat16 h[4]; uint2 u; } pk;
    pk.h[0] = __float2bfloat16(v.x); pk.h[1] = __float2bfloat16(v.y);
    pk.h[2] = __float2bfloat16(v.z); pk.h[3] = __float2bfloat16(v.w);
    *reinterpret_cast<uint2*>(dst + i) = pk.u;
}

// ---------------------------------------------------------------------------
// Kernel 7: MFMA attention core (swapped scores).
// Block = 4 waves, 64 s-rows of one (b,h).  Wave w owns s-cols w*16..w*16+15.
// scores^T[k][s] = sum_d KEqT[k][d]*Q[s][d]  (A=KEqT, B=Q^T, both 16B/lane global)
// softmax over k: lane-local 64 vals + shfl_xor(16,32).
// P^T packed bf16 -> XOR-swizzled LDS [s][k]; PV reads A=P via ds_read_b128.
// ---------------------------------------------------------------------------
__global__ __launch_bounds__(256) void k_attn(
    const __hip_bfloat16* __restrict__ Qb, const __hip_bfloat16* __restrict__ KEqT,
    const float* __restrict__ c0, const __hip_bfloat16* __restrict__ VFT,
    __hip_bfloat16* __restrict__ cat)
{
    __shared__ __align__(16) __hip_bfloat16 Pl[64 * 256]; // 32 KB, swizzled
    __shared__ float c0L[256];
    __shared__ float linvL[64];
    const int bh = blockIdx.y, b = bh >> 4, h = bh & 15;
    const int s0 = blockIdx.x * 64;
    const int t = threadIdx.x;
    const int w = t >> 6, lane = t & 63, lc = lane & 15, g = lane >> 4;

    c0L[t] = c0[(size_t)bh * 256 + t];

    // ---- scores ----
    const __hip_bfloat16* Ab = KEqT + (size_t)bh * (256 * 64);
    const __hip_bfloat16* Bq = Qb + ((size_t)b * Sn + s0 + w * 16 + lc) * 64 + g * 8;
    bhalf8 bq0 = *reinterpret_cast<const bhalf8*>(Bq);
    bhalf8 bq1 = *reinterpret_cast<const bhalf8*>(Bq + 32);

    floatx4 acc[16];
#pragma unroll
    for (int rt = 0; rt < 16; rt++) acc[rt] = (floatx4){0.f, 0.f, 0.f, 0.f};
#pragma unroll
    for (int rt = 0; rt < 16; rt++) {
        const __hip_bfloat16* ap = Ab + (rt * 16 + lc) * 64 + g * 8;
        bhalf8 a0 = *reinterpret_cast<const bhalf8*>(ap);
        bhalf8 a1 = *reinterpret_cast<const bhalf8*>(ap + 32);
        acc[rt] = __builtin_amdgcn_mfma_f32_16x16x32_bf16(a0, bq0, acc[rt], 0, 0, 0);
        acc[rt] = __builtin_amdgcn_mfma_f32_16x16x32_bf16(a1, bq1, acc[rt], 0, 0, 0);
    }
    __syncthreads(); // c0L ready

    // ---- softmax over k (rows of scores^T) ----
    float mx = -1e30f;
#pragma unroll
    for (int rt = 0; rt < 16; rt++)
#pragma unroll
        for (int i = 0; i < 4; i++) {
            float s = (acc[rt][i] + c0L[rt * 16 + g * 4 + i]) * 0.125f;
            acc[rt][i] = s;
            mx = fmaxf(mx, s);
        }
    mx = fmaxf(mx, __shfl_xor(mx, 16));
    mx = fmaxf(mx, __shfl_xor(mx, 32));
    float ls = 0.f;
#pragma unroll
    for (int rt = 0; rt < 16; rt++)
#pragma unroll
        for (int i = 0; i < 4; i++) {
            float e = __expf(acc[rt][i] - mx);
            acc[rt][i] = e;
            ls += e;
        }
    ls += __shfl_xor(ls, 16);
    ls += __shfl_xor(ls, 32);
    const int sL = w * 16 + lc;
    if (g == 0) linvL[sL] = 1.f / ls;

    // ---- pack P (unnormalized) bf16 into swizzled LDS [s][k] ----
#pragma unroll
    for (int rt = 0; rt < 16; rt++) {
        union { __hip_bfloat16 hh[4]; uint2 u; } pk;
#pragma unroll
        for (int i = 0; i < 4; i++) pk.hh[i] = __float2bfloat16(acc[rt][i]);
        int byt = sL * 512 + ((rt * 32 + g * 8) ^ ((sL & 7) << 4));
        *reinterpret_cast<uint2*>(reinterpret_cast<char*>(Pl) + byt) = pk.u;
    }
    __syncthreads();

    // ---- PV: out[s][e] = sum_k P[s][k] * VFT[e][k] ----
    const __hip_bfloat16* Vb = VFT + (size_t)bh * (64 * 256);
    floatx4 o[4];
#pragma unroll
    for (int dt = 0; dt < 4; dt++) o[dt] = (floatx4){0.f, 0.f, 0.f, 0.f};
#pragma unroll
    for (int ks = 0; ks < 8; ks++) {
        int byt = sL * 512 + ((ks * 64 + g * 16) ^ ((sL & 7) << 4));
        bhalf8 pa = *reinterpret_cast<const bhalf8*>(reinterpret_cast<const char*>(Pl) + byt);
#pragma unroll
        for (int dt = 0; dt < 4; dt++) {
            bhalf8 bv = *reinterpret_cast<const bhalf8*>(Vb + (dt * 16 + lc) * 256 + ks * 32 + g * 8);
            o[dt] = __builtin_amdgcn_mfma_f32_16x16x32_bf16(pa, bv, o[dt], 0, 0, 0);
        }
    }

    // ---- epilogue: normalize, exact GELU, bf16 store ----
#pragma unroll
    for (int dt = 0; dt < 4; dt++)
#pragma unroll
        for (int i = 0; i < 4; i++) {
            int sr = w * 16 + g * 4 + i;
            float x = o[dt][i] * linvL[sr];
            float y = 0.5f * x * (1.0f + erff(x * 0.70710678118654752f));
            cat[((size_t)b * Sn + s0 + sr) * 1024 + h * 64 + dt * 16 + lc] = __float2bfloat16(y);
        }
}

// ---------------------------------------------------------------------------
// Kernel 8: MFMA final projection.  out[m,c] = sum_f cat[m,f]*wo[c,f] + wo_b[c]
// 128x128 block tile, 4 waves (2x2), fragments direct from global (L2-hot).
// ---------------------------------------------------------------------------
__global__ __launch_bounds__(256) void k_out(
    const __hip_bfloat16* __restrict__ cat, const __hip_bfloat16* __restrict__ wo16,
    const float* __restrict__ wob, float* __restrict__ out)
{
    const int t = threadIdx.x;
    const int w = t >> 6, lane = t & 63, lc = lane & 15, g = lane >> 4;
    const int m0 = blockIdx.y * 128 + (w >> 1) * 64;
    const int n0 = blockIdx.x * 128 + (w & 1) * 64;
    floatx4 acc[4][4];
#pragma unroll
    for (int mt = 0; mt < 4; mt++)
#pragma unroll
        for (int nt = 0; nt < 4; nt++) acc[mt][nt] = (floatx4){0.f, 0.f, 0.f, 0.f};

#pragma unroll 2
    for (int kc = 0; kc < 1024; kc += 32) {
        bhalf8 af[4], bfr[4];
#pragma unroll
        for (int mt = 0; mt < 4; mt++)
            af[mt] = *reinterpret_cast<const bhalf8*>(cat + ((size_t)m0 + mt * 16 + lc) * 1024 + kc + g * 8);
#pragma unroll
        for (int nt = 0; nt < 4; nt++)
            bfr[nt] = *reinterpret_cast<const bhalf8*>(wo16 + ((size_t)n0 + nt * 16 + lc) * 1024 + kc + g * 8);
#pragma unroll
        for (int mt = 0; mt < 4; mt++)
#pragma unroll
            for (int nt = 0; nt < 4; nt++)
                acc[mt][nt] = __builtin_amdgcn_mfma_f32_16x16x32_bf16(af[mt], bfr[nt], acc[mt][nt], 0, 0, 0);
    }
#pragma unroll
    for (int mt = 0; mt < 4; mt++)
#pragma unroll
        for (int nt = 0; nt < 4; nt++)
#pragma unroll
            for (int i = 0; i < 4; i++) {
                int row = m0 + mt * 16 + g * 4 + i;
                int col = n0 + nt * 16 + lc;
                out[(size_t)row * 1024 + col] = acc[mt][nt][i] + wob[col];
            }
}

// ---------------------------------------------------------------------------
extern "C" void kernel_launch(void* const* d_in, const int* in_sizes, int n_in,
                              void* d_out, int out_size, void* d_ws, size_t ws_size,
                              hipStream_t stream) {
    const float* tensor = (const float*)d_in[0];
    const float* to_q   = (const float*)d_in[1];
    const float* to_k   = (const float*)d_in[2];
    const float* to_v   = (const float*)d_in[3];
    const float* wq     = (const float*)d_in[4];
    const float* wqb    = (const float*)d_in[5];
    const float* wk     = (const float*)d_in[6];
    const float* wkb    = (const float*)d_in[7];
    const float* wv     = (const float*)d_in[8];
    const float* wvb    = (const float*)d_in[9];
    const float* Ew     = (const float*)d_in[10];
    const float* Eb     = (const float*)d_in[11];
    const float* Fw     = (const float*)d_in[12];
    const float* Fb     = (const float*)d_in[13];
    const float* wo     = (const float*)d_in[14];
    const float* wob    = (const float*)d_in[15];
    float* out = (float*)d_out;

    // workspace layout (f32 slot units)
    float* ws   = (float*)d_ws;
    float* Kp   = ws;                  // 2097152
    float* Vp   = Kp + 2097152;        // 2097152
    float* Kc   = Vp + 2097152;        // 131072
    float* Vc   = Kc + 131072;         // 131072
    float* sumE = Vc + 131072;         // 256
    float* sumF = sumE + 256;          // 256
    float* Wqk  = sumF + 256;          // 65536
    float* u    = Wqk + 65536;         // 1024
    float* g    = u + 1024;            // 1024
    float* cw   = g + 1024;            // 1024
    float* cu   = cw + 1024;           // 16
    float* cg   = cu + 16;             // 16
    float* c0   = cg + 16;             // 32768
    float* fend = c0 + 32768;
    __hip_bfloat16* Qbuf  = (__hip_bfloat16*)fend;           // 2097152 bf16
    __hip_bfloat16* KEqT  = Qbuf + 2097152;                  // 2097152 bf16
    __hip_bfloat16* VFT   = KEqT + 2097152;                  // 2097152 bf16
    __hip_bfloat16* wo16  = VFT + 2097152;                   // 1048576 bf16
    __hip_bfloat16* cat   = wo16 + 1048576;                  // 33554432 bf16

    size_t need = ((char*)(cat + (size_t)BS * 1024)) - (char*)d_ws;
    if (ws_size < need) return;

    k_qkv<<<dim3(BS / 64), 256, 0, stream>>>(tensor, to_q, to_k, to_v, Qbuf, Kp, Vp);
    k_rowsum<<<dim3(Kn, 2), 256, 0, stream>>>(Ew, Fw, sumE, sumF);
    k_compress<<<dim3(4, Bn, 2), 256, 0, stream>>>(Ew, Fw, Kp, Vp, Kc, Vc);
    k_headw<<<dim3(Hn), 256, 0, stream>>>(wq, wqb, wk, wkb, Wqk, u, g, cw, cu, cg);
    k_keq<<<dim3(Hn, Bn), 256, 65536, stream>>>(Kc, Wqk, u, g, cw, cu, cg, sumE, Eb, KEqT, c0);
    k_vf<<<dim3(Hn, Bn), 256, 65536, stream>>>(Vc, wv, wvb, sumF, Fb, VFT);
    k_cast<<<dim3(1024), 256, 0, stream>>>(wo, wo16);
    k_attn<<<dim3(Sn / 64, Bn * Hn), 256, 0, stream>>>(Qbuf, KEqT, c0, VFT, cat);
    k_out<<<dim3(Cn / 128, BS / 128), 256, 0, stream>>>(cat, wo16, wob, out);
}

// Round 3
// 806.756 us; speedup vs baseline: 7.9859x; 1.3209x over previous
//
#include <hip/hip_runtime.h>
#include <hip/hip_bf16.h>
#include <math.h>

// Problem constants
constexpr int Bn = 8, Sn = 4096, Cn = 1024, Hn = 16, Dn = 64, Kn = 256;
constexpr int BS = Bn * Sn; // 32768

typedef __attribute__((ext_vector_type(8))) short bhalf8;
typedef __attribute__((ext_vector_type(4))) float floatx4;

// ---------------------------------------------------------------------------
// Generic f32 -> bf16 cast (exact multiples of 1024 floats).
// ---------------------------------------------------------------------------
__global__ __launch_bounds__(256) void k_cast(const float* __restrict__ src, __hip_bfloat16* __restrict__ dst)
{
    int i = (blockIdx.x * 256 + threadIdx.x) * 4;
    float4 v = *reinterpret_cast<const float4*>(src + i);
    union { __hip_bfloat16 h[4]; uint2 u; } pk;
    pk.h[0] = __float2bfloat16(v.x); pk.h[1] = __float2bfloat16(v.y);
    pk.h[2] = __float2bfloat16(v.z); pk.h[3] = __float2bfloat16(v.w);
    *reinterpret_cast<uint2*>(dst + i) = pk.u;
}

// ---------------------------------------------------------------------------
// Kernel 1: fused QKV shared projection, bf16 MFMA.
// M=32768 (tile 64), N=192 (q|k|v), K=1024 (slab 64).
// A: tensor f32 -> cvt bf16 -> XOR-swizzled LDS -> ds_read_b128 fragments.
// B: pre-cast bf16 weights Wb[192][1024], fragments direct from global (L2).
// Wave grid 2x2: wave tile 32m x 96n.
// ---------------------------------------------------------------------------
__global__ __launch_bounds__(256) void k_qkv(const float* __restrict__ tensor,
    const __hip_bfloat16* __restrict__ Wb,
    __hip_bfloat16* __restrict__ Qb, float* __restrict__ Kp, float* __restrict__ Vp)
{
    __shared__ __align__(16) char Al[64 * 128]; // 64 rows x 64 bf16, swizzled
    const int t = threadIdx.x;
    const int w = t >> 6, lane = t & 63, lc = lane & 15, g = lane >> 4;
    const int m0 = blockIdx.x * 64;
    const int wm = (w >> 1) * 32, wn = (w & 1) * 96;
    const int lrow = t >> 2, lq = t & 3;

    floatx4 acc[2][6];
#pragma unroll
    for (int mt = 0; mt < 2; mt++)
#pragma unroll
        for (int nt = 0; nt < 6; nt++) acc[mt][nt] = (floatx4){0.f, 0.f, 0.f, 0.f};

    const float* arow = tensor + (size_t)(m0 + lrow) * 1024;
    float4 f[4];
#pragma unroll
    for (int j = 0; j < 4; j++) f[j] = *reinterpret_cast<const float4*>(arow + (lq + j * 4) * 4);

    for (int kc = 0; kc < 1024; kc += 64) {
        __syncthreads(); // prior compute done reading LDS
#pragma unroll
        for (int j = 0; j < 4; j++) {
            union { __hip_bfloat16 h[4]; uint2 u; } pk;
            pk.h[0] = __float2bfloat16(f[j].x);
            pk.h[1] = __float2bfloat16(f[j].y);
            pk.h[2] = __float2bfloat16(f[j].z);
            pk.h[3] = __float2bfloat16(f[j].w);
            int byt = lrow * 128 + (((lq + j * 4) * 8) ^ ((lrow & 7) << 4));
            *reinterpret_cast<uint2*>(Al + byt) = pk.u;
        }
        __syncthreads();
        // preload next slab under compute
        int kcn = (kc + 64 < 1024) ? kc + 64 : 0;
#pragma unroll
        for (int j = 0; j < 4; j++) f[j] = *reinterpret_cast<const float4*>(arow + kcn + (lq + j * 4) * 4);
#pragma unroll
        for (int ks = 0; ks < 2; ks++) {
            bhalf8 a[2];
#pragma unroll
            for (int mt = 0; mt < 2; mt++) {
                int row = wm + mt * 16 + lc;
                a[mt] = *reinterpret_cast<const bhalf8*>(Al + row * 128 + ((ks * 64 + g * 16) ^ ((row & 7) << 4)));
            }
#pragma unroll
            for (int nt = 0; nt < 6; nt++) {
                bhalf8 bf = *reinterpret_cast<const bhalf8*>(&Wb[(size_t)(wn + nt * 16 + lc) * 1024 + kc + ks * 32 + g * 8]);
#pragma unroll
                for (int mt = 0; mt < 2; mt++)
                    acc[mt][nt] = __builtin_amdgcn_mfma_f32_16x16x32_bf16(a[mt], bf, acc[mt][nt], 0, 0, 0);
            }
        }
    }
#pragma unroll
    for (int mt = 0; mt < 2; mt++)
#pragma unroll
        for (int nt = 0; nt < 6; nt++) {
            int n = wn + nt * 16 + lc;
#pragma unroll
            for (int i = 0; i < 4; i++) {
                size_t s = (size_t)m0 + wm + mt * 16 + g * 4 + i;
                float v = acc[mt][nt][i];
                if (n < 64)       Qb[s * 64 + n] = __float2bfloat16(v);
                else if (n < 128) Kp[s * 64 + (n - 64)] = v;
                else              Vp[s * 64 + (n - 128)] = v;
            }
        }
}

// ---------------------------------------------------------------------------
// Kernel 2: row sums of E_w and F_w over S (f32, exact).
// ---------------------------------------------------------------------------
__global__ __launch_bounds__(256) void k_rowsum(const float* __restrict__ E, const float* __restrict__ F,
                                                float* __restrict__ sumE, float* __restrict__ sumF)
{
    __shared__ float red[256];
    const float* src = blockIdx.y ? F : E;
    float* dst = blockIdx.y ? sumF : sumE;
    const int k = blockIdx.x;
    const int t = threadIdx.x;
    float a = 0.f;
#pragma unroll
    for (int i = 0; i < 16; i++) a += src[(size_t)k * Sn + t + i * 256];
    red[t] = a;
    __syncthreads();
    for (int s = 128; s > 0; s >>= 1) {
        if (t < s) red[t] += red[t + s];
        __syncthreads();
    }
    if (t == 0) dst[k] = red[0];
}

// ---------------------------------------------------------------------------
// Kernel 3: sequence compression (f32 VALU).  Kc16[b,k,d] = bf16(sum_s E[k,s]*Kp[b,s,d])
// ---------------------------------------------------------------------------
__global__ __launch_bounds__(256) void k_compress(const float* __restrict__ E, const float* __restrict__ F,
    const float* __restrict__ Kp, const float* __restrict__ Vp,
    __hip_bfloat16* __restrict__ Kc16, __hip_bfloat16* __restrict__ Vc16)
{
    __shared__ float Es[64 * 33];
    __shared__ float Ps[32 * 64];
    const float* A = blockIdx.z ? F : E;
    const float* Bm = blockIdx.z ? Vp : Kp;
    __hip_bfloat16* dst = blockIdx.z ? Vc16 : Kc16;
    const int b = blockIdx.y;
    const int k0 = blockIdx.x * 64;
    const int t = threadIdx.x, tx = t & 15, ty = t >> 4;
    float acc[4][4] = {};
    for (int sc = 0; sc < Sn; sc += 32) {
#pragma unroll
        for (int ii = 0; ii < 2; ii++) {
            int idx4 = t + ii * 256;
            int row = idx4 >> 3, col4 = idx4 & 7;
            float4 v = *reinterpret_cast<const float4*>(&A[(size_t)(k0 + row) * Sn + sc + col4 * 4]);
            float* d2 = &Es[row * 33 + col4 * 4];
            d2[0] = v.x; d2[1] = v.y; d2[2] = v.z; d2[3] = v.w;
        }
#pragma unroll
        for (int ii = 0; ii < 2; ii++) {
            int idx4 = t + ii * 256;
            int row = idx4 >> 4, col4 = idx4 & 15;
            float4 v = *reinterpret_cast<const float4*>(&Bm[((size_t)b * Sn + sc + row) * Dn + col4 * 4]);
            float* d2 = &Ps[row * 64 + col4 * 4];
            d2[0] = v.x; d2[1] = v.y; d2[2] = v.z; d2[3] = v.w;
        }
        __syncthreads();
#pragma unroll 8
        for (int kk = 0; kk < 32; kk++) {
            float a[4], w[4];
#pragma unroll
            for (int i = 0; i < 4; i++) a[i] = Es[(ty * 4 + i) * 33 + kk];
#pragma unroll
            for (int j = 0; j < 4; j++) w[j] = Ps[kk * 64 + tx * 4 + j];
#pragma unroll
            for (int i = 0; i < 4; i++)
#pragma unroll
                for (int j = 0; j < 4; j++) acc[i][j] = fmaf(a[i], w[j], acc[i][j]);
        }
        __syncthreads();
    }
#pragma unroll
    for (int i = 0; i < 4; i++) {
        union { __hip_bfloat16 h[4]; uint2 u; } pk;
#pragma unroll
        for (int j = 0; j < 4; j++) pk.h[j] = __float2bfloat16(acc[i][j]);
        *reinterpret_cast<uint2*>(&dst[((size_t)b * Kn + k0 + ty * 4 + i) * Dn + tx * 4]) = pk.u;
    }
}

// ---------------------------------------------------------------------------
// Kernel 4: per-head combined weights (Wqk16 = bf16(wq^T wk), plus bias folds).
// ---------------------------------------------------------------------------
__global__ __launch_bounds__(256) void k_headw(const float* __restrict__ wq, const float* __restrict__ wqb,
    const float* __restrict__ wk, const float* __restrict__ wkb,
    __hip_bfloat16* __restrict__ Wqk16, float* __restrict__ uArr, float* __restrict__ gArr,
    float* __restrict__ cw, float* __restrict__ cu, float* __restrict__ cg)
{
    __shared__ float wqL[64 * 64], wkL[64 * 64];
    const int h = blockIdx.x, t = threadIdx.x;
#pragma unroll
    for (int ii = 0; ii < 4; ii++) {
        int idx4 = (t + ii * 256) * 4;
        *reinterpret_cast<float4*>(&wqL[idx4]) = *reinterpret_cast<const float4*>(&wq[(size_t)h * 4096 + idx4]);
        *reinterpret_cast<float4*>(&wkL[idx4]) = *reinterpret_cast<const float4*>(&wk[(size_t)h * 4096 + idx4]);
    }
    __syncthreads();
#pragma unroll 2
    for (int ii = 0; ii < 16; ii++) {
        int idx = t + ii * 256;
        int d = idx >> 6, dp = idx & 63;
        float acc = 0.f;
        for (int e = 0; e < 64; e++) acc = fmaf(wqL[e * 64 + d], wkL[e * 64 + dp], acc);
        Wqk16[(size_t)h * 4096 + idx] = __float2bfloat16(acc);
    }
    if (t < 64) {
        int d = t;
        float au = 0.f, ag = 0.f, aw = 0.f;
        for (int e = 0; e < 64; e++) {
            float q = wqL[e * 64 + d];
            au = fmaf(q, wkb[h * 64 + e], au);
            ag += q;
            aw = fmaf(wqb[h * 64 + e], wkL[e * 64 + d], aw);
        }
        uArr[h * 64 + d] = au; gArr[h * 64 + d] = ag; cw[h * 64 + d] = aw;
    }
    if (t == 0) {
        float acu = 0.f, acg = 0.f;
        for (int e = 0; e < 64; e++) {
            acu = fmaf(wqb[h * 64 + e], wkb[h * 64 + e], acu);
            acg += wqb[h * 64 + e];
        }
        cu[h] = acu; cg[h] = acg;
    }
}

// ---------------------------------------------------------------------------
// Kernel 5: fused per-(b,h) projections, all-MFMA, no LDS.
//  KEqT[k][d] : A=Wqk16 (M=d=64), B=Kc16 (N=k=256), Kdim=dp=64
//  VFT[e][k]  : A=Vc16  (M=k=256), B=wv16 (N=e=64),  Kdim=dp=64
//  c0[k]      : VALU dot (cw . Kc[k]) + bias terms
// Operand order chosen so each lane's 4 C-values are memory-consecutive.
// ---------------------------------------------------------------------------
__global__ __launch_bounds__(256) void k_proj(
    const __hip_bfloat16* __restrict__ Kc16, const __hip_bfloat16* __restrict__ Vc16,
    const __hip_bfloat16* __restrict__ Wqk16, const __hip_bfloat16* __restrict__ wv16,
    const float* __restrict__ uArr, const float* __restrict__ gArr,
    const float* __restrict__ cw, const float* __restrict__ cu, const float* __restrict__ cg,
    const float* __restrict__ sumE, const float* __restrict__ Eb,
    const float* __restrict__ sumF, const float* __restrict__ Fb,
    const float* __restrict__ wvb,
    __hip_bfloat16* __restrict__ KEqT, __hip_bfloat16* __restrict__ VFT, float* __restrict__ c0)
{
    const int h = blockIdx.x, b = blockIdx.y;
    const int bh = b * Hn + h;
    const int t = threadIdx.x;
    const int w = t >> 6, lane = t & 63, lc = lane & 15, g = lane >> 4;
    const __hip_bfloat16* KcB = Kc16 + (size_t)b * (Kn * 64);
    const __hip_bfloat16* VcB = Vc16 + (size_t)b * (Kn * 64);
    const __hip_bfloat16* Wq = Wqk16 + (size_t)h * 4096;
    const __hip_bfloat16* Wv = wv16 + (size_t)h * 4096;

    // ---- part 1: KEqT ----
    {
        floatx4 acc[4][4];
#pragma unroll
        for (int mt = 0; mt < 4; mt++)
#pragma unroll
            for (int nt = 0; nt < 4; nt++) acc[mt][nt] = (floatx4){0.f, 0.f, 0.f, 0.f};
#pragma unroll
        for (int ks = 0; ks < 2; ks++) {
            bhalf8 a[4];
#pragma unroll
            for (int mt = 0; mt < 4; mt++)
                a[mt] = *reinterpret_cast<const bhalf8*>(Wq + (mt * 16 + lc) * 64 + ks * 32 + g * 8);
#pragma unroll
            for (int nt = 0; nt < 4; nt++) {
                bhalf8 bf = *reinterpret_cast<const bhalf8*>(KcB + (size_t)(w * 64 + nt * 16 + lc) * 64 + ks * 32 + g * 8);
#pragma unroll
                for (int mt = 0; mt < 4; mt++)
                    acc[mt][nt] = __builtin_amdgcn_mfma_f32_16x16x32_bf16(a[mt], bf, acc[mt][nt], 0, 0, 0);
            }
        }
#pragma unroll
        for (int mt = 0; mt < 4; mt++) {
            float4 u4 = *reinterpret_cast<const float4*>(&uArr[h * 64 + mt * 16 + g * 4]);
            float4 g4 = *reinterpret_cast<const float4*>(&gArr[h * 64 + mt * 16 + g * 4]);
#pragma unroll
            for (int nt = 0; nt < 4; nt++) {
                int k = w * 64 + nt * 16 + lc;
                float sE = sumE[k], eb = Eb[k];
                union { __hip_bfloat16 hh[4]; uint2 uu; } pk;
                pk.hh[0] = __float2bfloat16(acc[mt][nt][0] + u4.x * sE + g4.x * eb);
                pk.hh[1] = __float2bfloat16(acc[mt][nt][1] + u4.y * sE + g4.y * eb);
                pk.hh[2] = __float2bfloat16(acc[mt][nt][2] + u4.z * sE + g4.z * eb);
                pk.hh[3] = __float2bfloat16(acc[mt][nt][3] + u4.w * sE + g4.w * eb);
                *reinterpret_cast<uint2*>(&KEqT[((size_t)bh * 256 + k) * 64 + mt * 16 + g * 4]) = pk.uu;
            }
        }
    }
    // ---- part 2: VFT ----
    {
        floatx4 acc[4][4];
#pragma unroll
        for (int mt = 0; mt < 4; mt++)
#pragma unroll
            for (int nt = 0; nt < 4; nt++) acc[mt][nt] = (floatx4){0.f, 0.f, 0.f, 0.f};
#pragma unroll
        for (int ks = 0; ks < 2; ks++) {
            bhalf8 a[4];
#pragma unroll
            for (int mt = 0; mt < 4; mt++)
                a[mt] = *reinterpret_cast<const bhalf8*>(VcB + (size_t)(w * 64 + mt * 16 + lc) * 64 + ks * 32 + g * 8);
#pragma unroll
            for (int nt = 0; nt < 4; nt++) {
                bhalf8 bf = *reinterpret_cast<const bhalf8*>(Wv + (nt * 16 + lc) * 64 + ks * 32 + g * 8);
#pragma unroll
                for (int mt = 0; mt < 4; mt++)
                    acc[mt][nt] = __builtin_amdgcn_mfma_f32_16x16x32_bf16(a[mt], bf, acc[mt][nt], 0, 0, 0);
            }
        }
#pragma unroll
        for (int mt = 0; mt < 4; mt++) {
            int kbase = w * 64 + mt * 16 + g * 4;
            float4 sF4 = *reinterpret_cast<const float4*>(&sumF[kbase]);
            float4 fb4 = *reinterpret_cast<const float4*>(&Fb[kbase]);
#pragma unroll
            for (int nt = 0; nt < 4; nt++) {
                int e = nt * 16 + lc;
                float wvbe = wvb[h * 64 + e];
                union { __hip_bfloat16 hh[4]; uint2 uu; } pk;
                pk.hh[0] = __float2bfloat16(acc[mt][nt][0] + wvbe * sF4.x + fb4.x);
                pk.hh[1] = __float2bfloat16(acc[mt][nt][1] + wvbe * sF4.y + fb4.y);
                pk.hh[2] = __float2bfloat16(acc[mt][nt][2] + wvbe * sF4.z + fb4.z);
                pk.hh[3] = __float2bfloat16(acc[mt][nt][3] + wvbe * sF4.w + fb4.w);
                *reinterpret_cast<uint2*>(&VFT[(size_t)bh * 16384 + (size_t)e * 256 + kbase]) = pk.uu;
            }
        }
    }
    // ---- part 3: c0 ----
    {
        const __hip_bfloat16* kr = KcB + (size_t)t * 64;
        float acc = 0.f;
#pragma unroll
        for (int dp = 0; dp < 64; dp++)
            acc = fmaf(cw[h * 64 + dp], __bfloat162float(kr[dp]), acc);
        c0[(size_t)bh * 256 + t] = acc + cu[h] * sumE[t] + cg[h] * Eb[t];
    }
}

// ---------------------------------------------------------------------------
// Kernel 7: MFMA attention core (swapped scores), unchanged from round 1.
// ---------------------------------------------------------------------------
__global__ __launch_bounds__(256) void k_attn(
    const __hip_bfloat16* __restrict__ Qb, const __hip_bfloat16* __restrict__ KEqT,
    const float* __restrict__ c0, const __hip_bfloat16* __restrict__ VFT,
    __hip_bfloat16* __restrict__ cat)
{
    __shared__ __align__(16) __hip_bfloat16 Pl[64 * 256]; // 32 KB, swizzled
    __shared__ float c0L[256];
    __shared__ float linvL[64];
    const int bh = blockIdx.y, b = bh >> 4, h = bh & 15;
    const int s0 = blockIdx.x * 64;
    const int t = threadIdx.x;
    const int w = t >> 6, lane = t & 63, lc = lane & 15, g = lane >> 4;

    c0L[t] = c0[(size_t)bh * 256 + t];

    const __hip_bfloat16* Ab = KEqT + (size_t)bh * (256 * 64);
    const __hip_bfloat16* Bq = Qb + ((size_t)b * Sn + s0 + w * 16 + lc) * 64 + g * 8;
    bhalf8 bq0 = *reinterpret_cast<const bhalf8*>(Bq);
    bhalf8 bq1 = *reinterpret_cast<const bhalf8*>(Bq + 32);

    floatx4 acc[16];
#pragma unroll
    for (int rt = 0; rt < 16; rt++) acc[rt] = (floatx4){0.f, 0.f, 0.f, 0.f};
#pragma unroll
    for (int rt = 0; rt < 16; rt++) {
        const __hip_bfloat16* ap = Ab + (rt * 16 + lc) * 64 + g * 8;
        bhalf8 a0 = *reinterpret_cast<const bhalf8*>(ap);
        bhalf8 a1 = *reinterpret_cast<const bhalf8*>(ap + 32);
        acc[rt] = __builtin_amdgcn_mfma_f32_16x16x32_bf16(a0, bq0, acc[rt], 0, 0, 0);
        acc[rt] = __builtin_amdgcn_mfma_f32_16x16x32_bf16(a1, bq1, acc[rt], 0, 0, 0);
    }
    __syncthreads(); // c0L ready

    float mx = -1e30f;
#pragma unroll
    for (int rt = 0; rt < 16; rt++)
#pragma unroll
        for (int i = 0; i < 4; i++) {
            float s = (acc[rt][i] + c0L[rt * 16 + g * 4 + i]) * 0.125f;
            acc[rt][i] = s;
            mx = fmaxf(mx, s);
        }
    mx = fmaxf(mx, __shfl_xor(mx, 16));
    mx = fmaxf(mx, __shfl_xor(mx, 32));
    float ls = 0.f;
#pragma unroll
    for (int rt = 0; rt < 16; rt++)
#pragma unroll
        for (int i = 0; i < 4; i++) {
            float e = __expf(acc[rt][i] - mx);
            acc[rt][i] = e;
            ls += e;
        }
    ls += __shfl_xor(ls, 16);
    ls += __shfl_xor(ls, 32);
    const int sL = w * 16 + lc;
    if (g == 0) linvL[sL] = 1.f / ls;

#pragma unroll
    for (int rt = 0; rt < 16; rt++) {
        union { __hip_bfloat16 hh[4]; uint2 u; } pk;
#pragma unroll
        for (int i = 0; i < 4; i++) pk.hh[i] = __float2bfloat16(acc[rt][i]);
        int byt = sL * 512 + ((rt * 32 + g * 8) ^ ((sL & 7) << 4));
        *reinterpret_cast<uint2*>(reinterpret_cast<char*>(Pl) + byt) = pk.u;
    }
    __syncthreads();

    const __hip_bfloat16* Vb = VFT + (size_t)bh * (64 * 256);
    floatx4 o[4];
#pragma unroll
    for (int dt = 0; dt < 4; dt++) o[dt] = (floatx4){0.f, 0.f, 0.f, 0.f};
#pragma unroll
    for (int ks = 0; ks < 8; ks++) {
        int byt = sL * 512 + ((ks * 64 + g * 16) ^ ((sL & 7) << 4));
        bhalf8 pa = *reinterpret_cast<const bhalf8*>(reinterpret_cast<const char*>(Pl) + byt);
#pragma unroll
        for (int dt = 0; dt < 4; dt++) {
            bhalf8 bv = *reinterpret_cast<const bhalf8*>(Vb + (dt * 16 + lc) * 256 + ks * 32 + g * 8);
            o[dt] = __builtin_amdgcn_mfma_f32_16x16x32_bf16(pa, bv, o[dt], 0, 0, 0);
        }
    }

#pragma unroll
    for (int dt = 0; dt < 4; dt++)
#pragma unroll
        for (int i = 0; i < 4; i++) {
            int sr = w * 16 + g * 4 + i;
            float x = o[dt][i] * linvL[sr];
            float y = 0.5f * x * (1.0f + erff(x * 0.70710678118654752f));
            cat[((size_t)b * Sn + s0 + sr) * 1024 + h * 64 + dt * 16 + lc] = __float2bfloat16(y);
        }
}

// ---------------------------------------------------------------------------
// Kernel 8: MFMA final projection, unchanged from round 1.
// ---------------------------------------------------------------------------
__global__ __launch_bounds__(256) void k_out(
    const __hip_bfloat16* __restrict__ cat, const __hip_bfloat16* __restrict__ wo16,
    const float* __restrict__ wob, float* __restrict__ out)
{
    const int t = threadIdx.x;
    const int w = t >> 6, lane = t & 63, lc = lane & 15, g = lane >> 4;
    const int m0 = blockIdx.y * 128 + (w >> 1) * 64;
    const int n0 = blockIdx.x * 128 + (w & 1) * 64;
    floatx4 acc[4][4];
#pragma unroll
    for (int mt = 0; mt < 4; mt++)
#pragma unroll
        for (int nt = 0; nt < 4; nt++) acc[mt][nt] = (floatx4){0.f, 0.f, 0.f, 0.f};

#pragma unroll 2
    for (int kc = 0; kc < 1024; kc += 32) {
        bhalf8 af[4], bfr[4];
#pragma unroll
        for (int mt = 0; mt < 4; mt++)
            af[mt] = *reinterpret_cast<const bhalf8*>(cat + ((size_t)m0 + mt * 16 + lc) * 1024 + kc + g * 8);
#pragma unroll
        for (int nt = 0; nt < 4; nt++)
            bfr[nt] = *reinterpret_cast<const bhalf8*>(wo16 + ((size_t)n0 + nt * 16 + lc) * 1024 + kc + g * 8);
#pragma unroll
        for (int mt = 0; mt < 4; mt++)
#pragma unroll
            for (int nt = 0; nt < 4; nt++)
                acc[mt][nt] = __builtin_amdgcn_mfma_f32_16x16x32_bf16(af[mt], bfr[nt], acc[mt][nt], 0, 0, 0);
    }
#pragma unroll
    for (int mt = 0; mt < 4; mt++)
#pragma unroll
        for (int nt = 0; nt < 4; nt++)
#pragma unroll
            for (int i = 0; i < 4; i++) {
                int row = m0 + mt * 16 + g * 4 + i;
                int col = n0 + nt * 16 + lc;
                out[(size_t)row * 1024 + col] = acc[mt][nt][i] + wob[col];
            }
}

// ---------------------------------------------------------------------------
extern "C" void kernel_launch(void* const* d_in, const int* in_sizes, int n_in,
                              void* d_out, int out_size, void* d_ws, size_t ws_size,
                              hipStream_t stream) {
    const float* tensor = (const float*)d_in[0];
    const float* to_q   = (const float*)d_in[1];
    const float* to_k   = (const float*)d_in[2];
    const float* to_v   = (const float*)d_in[3];
    const float* wq     = (const float*)d_in[4];
    const float* wqb    = (const float*)d_in[5];
    const float* wk     = (const float*)d_in[6];
    const float* wkb    = (const float*)d_in[7];
    const float* wv     = (const float*)d_in[8];
    const float* wvb    = (const float*)d_in[9];
    const float* Ew     = (const float*)d_in[10];
    const float* Eb     = (const float*)d_in[11];
    const float* Fw     = (const float*)d_in[12];
    const float* Fb     = (const float*)d_in[13];
    const float* wo     = (const float*)d_in[14];
    const float* wob    = (const float*)d_in[15];
    float* out = (float*)d_out;

    // workspace layout
    float* ws   = (float*)d_ws;
    float* Kp   = ws;                  // 2097152 f32
    float* Vp   = Kp + 2097152;        // 2097152 f32
    float* sumE = Vp + 2097152;        // 256
    float* sumF = sumE + 256;          // 256
    float* uArr = sumF + 256;          // 1024
    float* gArr = uArr + 1024;         // 1024
    float* cw   = gArr + 1024;         // 1024
    float* cu   = cw + 1024;           // 16
    float* cg   = cu + 16;             // 16
    float* c0   = cg + 16;             // 32768
    float* fend = c0 + 32768;
    __hip_bfloat16* Qb    = (__hip_bfloat16*)fend;           // 2097152
    __hip_bfloat16* KEqT  = Qb + 2097152;                    // 2097152
    __hip_bfloat16* VFT   = KEqT + 2097152;                  // 2097152
    __hip_bfloat16* wo16  = VFT + 2097152;                   // 1048576
    __hip_bfloat16* Wb    = wo16 + 1048576;                  // 196608
    __hip_bfloat16* Wqk16 = Wb + 196608;                     // 65536
    __hip_bfloat16* wv16  = Wqk16 + 65536;                   // 65536
    __hip_bfloat16* Kc16  = wv16 + 65536;                    // 131072
    __hip_bfloat16* Vc16  = Kc16 + 131072;                   // 131072
    __hip_bfloat16* cat   = Vc16 + 131072;                   // 33554432

    size_t need = ((char*)(cat + (size_t)BS * 1024)) - (char*)d_ws;
    if (ws_size < need) return;

    // casts (weights, tiny)
    k_cast<<<dim3(64),   256, 0, stream>>>(to_q, Wb);
    k_cast<<<dim3(64),   256, 0, stream>>>(to_k, Wb + 65536);
    k_cast<<<dim3(64),   256, 0, stream>>>(to_v, Wb + 131072);
    k_cast<<<dim3(1024), 256, 0, stream>>>(wo, wo16);
    k_cast<<<dim3(64),   256, 0, stream>>>(wv, wv16);

    k_qkv<<<dim3(BS / 64), 256, 0, stream>>>(tensor, Wb, Qb, Kp, Vp);
    k_rowsum<<<dim3(Kn, 2), 256, 0, stream>>>(Ew, Fw, sumE, sumF);
    k_compress<<<dim3(4, Bn, 2), 256, 0, stream>>>(Ew, Fw, Kp, Vp, Kc16, Vc16);
    k_headw<<<dim3(Hn), 256, 0, stream>>>(wq, wqb, wk, wkb, Wqk16, uArr, gArr, cw, cu, cg);
    k_proj<<<dim3(Hn, Bn), 256, 0, stream>>>(Kc16, Vc16, Wqk16, wv16, uArr, gArr, cw, cu, cg,
                                             sumE, Eb, sumF, Fb, wvb, KEqT, VFT, c0);
    k_attn<<<dim3(Sn / 64, Bn * Hn), 256, 0, stream>>>(Qb, KEqT, c0, VFT, cat);
    k_out<<<dim3(Cn / 128, BS / 128), 256, 0, stream>>>(cat, wo16, wob, out);
}